// Round 2
// baseline (2029.453 us; speedup 1.0000x reference)
//
#include <hip/hip_runtime.h>
#include <hip/hip_bf16.h>
#include <math.h>

using bf16 = __hip_bfloat16;

// ---------------- problem constants ----------------
constexpr int BB    = 4;
constexpr int Hh    = 112;
constexpr int Ww    = 112;
constexpr int C     = 256;
constexpr int L     = Hh * Ww;        // 12544
constexpr int HEADS = 8;
constexpr int WS    = 7;
constexpr int SHIFT = 3;
constexpr int HID   = 1024;
constexpr int HD    = 32;
constexpr int NWIN  = 49;             // tokens per window
constexpr int NW    = 256;            // windows per image (16x16)
constexpr int BT    = BB * NW;        // 1024 windows total
constexpr int M     = BT * NWIN;      // 50176 tokens (== B*L)
constexpr float SCALE = 0.17677669529663687f;  // 32^-0.5
constexpr float EPS   = 1e-5f;

// window-token r -> natural token index (b*L + h*W + w).
// Same map serves the forward gather (roll -3 + window_partition) and the
// reverse scatter (window_reverse + roll +3): both are (hp+3)%112.
__device__ __forceinline__ int src_row_idx(int r) {
    int b_ = r / NWIN;
    int n  = r - b_ * NWIN;
    int b  = b_ >> 8;          // / NW
    int w  = b_ & 255;
    int wh = w >> 4, ww = w & 15;
    int i  = n / WS, j = n - i * WS;
    int hp = wh * WS + i, wp = ww * WS + j;
    int h  = hp + SHIFT; if (h >= Hh) h -= Hh;
    int wc = wp + SHIFT; if (wc >= Ww) wc -= Ww;
    return b * L + h * Ww + wc;
}

// ---------------- per-token LN stats (mean, rstd) ----------------
__global__ __launch_bounds__(256)
void stats_kernel(const float* __restrict__ x, float* __restrict__ stats) {
    int wave = threadIdx.x >> 6, lane = threadIdx.x & 63;
    int tok  = blockIdx.x * 4 + wave;
    const float4 v = *(const float4*)&x[(size_t)tok * C + lane * 4];
    float s  = v.x + v.y + v.z + v.w;
    float s2 = v.x*v.x + v.y*v.y + v.z*v.z + v.w*v.w;
    #pragma unroll
    for (int o = 32; o > 0; o >>= 1) {
        s  += __shfl_down(s, o);
        s2 += __shfl_down(s2, o);
    }
    if (lane == 0) {
        float m   = s * (1.0f / C);
        float var = s2 * (1.0f / C) - m * m;
        stats[tok * 2]     = m;
        stats[tok * 2 + 1] = rsqrtf(var + EPS);
    }
}

// ---------------- vote-embed MLP (per window token) ----------------
__global__ __launch_bounds__(256)
void vemb_kernel(const float* __restrict__ vote,
                 const float* __restrict__ w1, const float* __restrict__ b1,
                 const float* __restrict__ w2, const float* __restrict__ b2,
                 bf16* __restrict__ vemb) {
    int r = blockIdx.x;
    int srow = src_row_idx(r);
    __shared__ float hv[16];
    __shared__ float vv[3];
    int t = threadIdx.x;
    if (t < 3) vv[t] = vote[(size_t)srow * 3 + t];
    __syncthreads();
    if (t < 16)
        hv[t] = fmaxf(w1[t*3]*vv[0] + w1[t*3+1]*vv[1] + w1[t*3+2]*vv[2] + b1[t], 0.f);
    __syncthreads();
    float acc = b2[t];
    #pragma unroll
    for (int o = 0; o < 16; ++o) acc += hv[o] * w2[t * 16 + o];
    vemb[(size_t)r * C + t] = __float2bfloat16(acc);
}

// ---------------- tiled GEMM: out = A @ W^T (+ fused pieces) -------------
enum { MODE_QKV = 0, MODE_PROJ = 1, MODE_FC1 = 2, MODE_FC2 = 3 };

template <int MODE>
__global__ __launch_bounds__(256)
void gemm_kernel(const void* __restrict__ Asrc_, const float* __restrict__ W,
                 const float* __restrict__ bias, const float* __restrict__ stats,
                 const float* __restrict__ gamma, const float* __restrict__ beta,
                 const void* __restrict__ addsrc_, void* __restrict__ outp_) {
    constexpr int  K   = (MODE == MODE_FC2) ? 1024 : 256;
    constexpr bool ABF = (MODE == MODE_PROJ) || (MODE == MODE_FC2);  // A is bf16
    constexpr bool LN  = (MODE == MODE_QKV) || (MODE == MODE_FC1);
    constexpr int BM = 64, BN = 64, BK = 16;
    const float* Af = (const float*)Asrc_;
    const bf16*  Ab = (const bf16*)Asrc_;
    __shared__ float As[BK][BM];
    __shared__ float Bs[BK][BN];
    int tid = threadIdx.x;
    int tm = tid & 15, tn = tid >> 4;
    int mBase = blockIdx.x * BM, nBase = blockIdx.y * BN;
    int loadK   = tid & 15;
    int loadRow = tid >> 4;

    int arow[4]; float amean[4], arstd[4];
    #pragma unroll
    for (int p = 0; p < 4; ++p) {
        int r = mBase + loadRow + p * 16;
        int srow = (MODE == MODE_QKV) ? src_row_idx(r) : r;
        arow[p] = srow;
        if constexpr (LN) {
            amean[p] = stats[srow * 2];
            arstd[p] = stats[srow * 2 + 1];
        }
    }

    float acc[4][4] = {};
    for (int k0 = 0; k0 < K; k0 += BK) {
        #pragma unroll
        for (int p = 0; p < 4; ++p) {
            int k = k0 + loadK;
            float a;
            if constexpr (ABF) a = __bfloat162float(Ab[(size_t)arow[p] * K + k]);
            else               a = Af[(size_t)arow[p] * K + k];
            if constexpr (LN)
                a = (a - amean[p]) * arstd[p] * gamma[k] + beta[k];
            As[loadK][loadRow + p * 16] = a;
        }
        #pragma unroll
        for (int p = 0; p < 4; ++p)
            Bs[loadK][loadRow + p * 16] =
                W[(size_t)(nBase + loadRow + p * 16) * K + k0 + loadK];
        __syncthreads();
        #pragma unroll
        for (int kk = 0; kk < BK; ++kk) {
            float4 av = *(const float4*)&As[kk][tm * 4];
            float4 bv = *(const float4*)&Bs[kk][tn * 4];
            float aa[4] = {av.x, av.y, av.z, av.w};
            float bb[4] = {bv.x, bv.y, bv.z, bv.w};
            #pragma unroll
            for (int i = 0; i < 4; ++i)
                #pragma unroll
                for (int j = 0; j < 4; ++j)
                    acc[i][j] = fmaf(aa[i], bb[j], acc[i][j]);
        }
        __syncthreads();
    }

    #pragma unroll
    for (int i = 0; i < 4; ++i) {
        int r = mBase + tm * 4 + i;
        int dst = (MODE == MODE_PROJ) ? src_row_idx(r) : r;
        #pragma unroll
        for (int j = 0; j < 4; ++j) {
            int c = nBase + tn * 4 + j;
            float v = acc[i][j] + bias[c];
            if constexpr (MODE == MODE_QKV) {
                float ve = __bfloat162float(((const bf16*)addsrc_)[(size_t)r * 256 + (c & 255)]);
                v += (c >= 512) ? 2.f * ve : ve;    // v-path carries qkv2 + 2*vemb
                ((bf16*)outp_)[(size_t)r * 768 + c] = __float2bfloat16(v);
            } else if constexpr (MODE == MODE_PROJ) {
                ((float*)outp_)[(size_t)dst * 256 + c] =
                    ((const float*)addsrc_)[(size_t)dst * 256 + c] + v;
            } else if constexpr (MODE == MODE_FC1) {
                float g = 0.5f * v * (1.f + erff(v * 0.70710678118f));
                ((bf16*)outp_)[(size_t)r * 1024 + c] = __float2bfloat16(g);
            } else {  // FC2: final residual add, write f32 output
                ((float*)outp_)[(size_t)r * 256 + c] =
                    ((const float*)addsrc_)[(size_t)r * 256 + c] + v;
            }
        }
    }
}

// ---------------- per-(window, head) cosine attention ----------------
__global__ __launch_bounds__(256)
void attn_kernel(const bf16* __restrict__ qkv, const float* __restrict__ polar,
                 const float* __restrict__ rw1, const float* __restrict__ rb1,
                 const float* __restrict__ rw2, const float* __restrict__ rb2,
                 const float* __restrict__ tau, const float* __restrict__ mask,
                 bf16* __restrict__ outp) {
    int b_   = blockIdx.x >> 3;
    int head = blockIdx.x & 7;
    int t    = threadIdx.x;

    constexpr int SP = 53;   // transposed row stride (odd -> conflict-free columns)
    __shared__ float qsT[HD * SP], ksT[HD * SP], vsT[HD * SP];
    __shared__ float at[NWIN * 50];
    __shared__ float pwx[NWIN], pwy[NWIN];
    __shared__ float qn[NWIN], kn[NWIN];
    __shared__ float cw1[32], cb1[16], cw2[16];

    for (int idx = t; idx < NWIN * HD; idx += 256) {
        int n = idx >> 5, d = idx & 31;
        size_t row = ((size_t)b_ * NWIN + n) * 768 + head * HD + d;
        qsT[d * SP + n] = __bfloat162float(qkv[row]);
        ksT[d * SP + n] = __bfloat162float(qkv[row + 256]);
        vsT[d * SP + n] = __bfloat162float(qkv[row + 512]);
    }
    if (t < 98) {
        int n = t >> 1, cix = t & 1;
        int srow = src_row_idx(b_ * NWIN + n);
        float v = polar[(size_t)srow * 2 + cix];
        if (cix) pwy[n] = v; else pwx[n] = v;
    }
    if (t >= 128 && t < 160) cw1[t - 128] = rw1[t - 128];
    else if (t >= 160 && t < 176) cb1[t - 160] = rb1[t - 160];
    else if (t >= 176 && t < 192) cw2[t - 176] = rw2[head * 16 + (t - 176)];
    __syncthreads();

    if (t < NWIN) {
        float s = 0;
        #pragma unroll
        for (int d = 0; d < HD; ++d) { float v = qsT[d * SP + t]; s += v * v; }
        qn[t] = sqrtf(s);
    } else if (t >= 64 && t < 64 + NWIN) {
        int n = t - 64; float s = 0;
        #pragma unroll
        for (int d = 0; d < HD; ++d) { float v = ksT[d * SP + n]; s += v * v; }
        kn[n] = sqrtf(s);
    }
    __syncthreads();

    float tauc = fmaxf(tau[head], 0.01f);
    float rb2h = rb2[head];
    const float* mrow = mask + (size_t)(b_ & 255) * NWIN * NWIN;

    for (int e = t; e < NWIN * NWIN; e += 256) {
        int n = e / NWIN, m = e - n * NWIN;
        float dot = 0;
        #pragma unroll
        for (int d = 0; d < HD; ++d)
            dot = fmaf(qsT[d * SP + n], ksT[d * SP + m], dot);
        float a = dot * SCALE / fmaxf(qn[n] * kn[m], 1e-6f) / tauc;
        float dx = pwx[n] - pwx[m], dy = pwy[n] - pwy[m];
        float racc = rb2h;
        #pragma unroll
        for (int o = 0; o < 16; ++o)
            racc = fmaf(fmaxf(fmaf(cw1[2*o], dx, fmaf(cw1[2*o+1], dy, cb1[o])), 0.f),
                        cw2[o], racc);
        at[n * 50 + m] = a + racc + mrow[e];
    }
    __syncthreads();

    if (t < NWIN) {
        float mx = -1e30f;
        for (int m = 0; m < NWIN; ++m) mx = fmaxf(mx, at[t * 50 + m]);
        float s = 0;
        for (int m = 0; m < NWIN; ++m) {
            float ev = expf(at[t * 50 + m] - mx);
            at[t * 50 + m] = ev; s += ev;
        }
        float inv = 1.f / s;
        for (int m = 0; m < NWIN; ++m) at[t * 50 + m] *= inv;
    }
    __syncthreads();

    for (int e = t; e < NWIN * HD; e += 256) {
        int n = e >> 5, d = e & 31;
        float acc = 0;
        #pragma unroll
        for (int m = 0; m < NWIN; ++m)
            acc = fmaf(at[n * 50 + m], vsT[d * SP + m], acc);
        outp[((size_t)b_ * NWIN + n) * C + head * HD + d] = __float2bfloat16(acc);
    }
}

// ---------------- launch ----------------
extern "C" void kernel_launch(void* const* d_in, const int* in_sizes, int n_in,
                              void* d_out, int out_size, void* d_ws, size_t ws_size,
                              hipStream_t stream) {
    const float* x     = (const float*)d_in[0];
    const float* mask  = (const float*)d_in[1];
    const float* polar = (const float*)d_in[2];
    const float* vote  = (const float*)d_in[3];
    const float* g1    = (const float*)d_in[4];
    const float* be1   = (const float*)d_in[5];
    const float* wqkv  = (const float*)d_in[6];
    const float* bqkv  = (const float*)d_in[7];
    const float* wproj = (const float*)d_in[8];
    const float* bproj = (const float*)d_in[9];
    const float* tau   = (const float*)d_in[10];
    const float* rw1   = (const float*)d_in[11];
    const float* rb1   = (const float*)d_in[12];
    const float* rw2   = (const float*)d_in[13];
    const float* rb2   = (const float*)d_in[14];
    const float* vw1   = (const float*)d_in[15];
    const float* vb1   = (const float*)d_in[16];
    const float* vw2   = (const float*)d_in[17];
    const float* vb2   = (const float*)d_in[18];
    const float* g2    = (const float*)d_in[19];
    const float* be2   = (const float*)d_in[20];
    const float* fc1w  = (const float*)d_in[21];
    const float* fc1b  = (const float*)d_in[22];
    const float* fc2w  = (const float*)d_in[23];
    const float* fc2b  = (const float*)d_in[24];
    float* out = (float*)d_out;

    // workspace layout (bytes), total = 129,253,376 B (~123.3 MiB):
    //   [0 .. 77,070,336)              qkv   bf16 [M][768]
    //   [77,070,336 .. 102,760,448)    vemb  bf16 [M][256]
    //   [102,760,448 .. 128,450,560)   attnout bf16 [M][256]
    //   [128,450,560 .. 129,253,376)   stats1, stats2 f32 [M][2] each
    // hbuf bf16 [M][1024] overlays qkv+vemb exactly (both dead by fc1).
    char* base = (char*)d_ws;
    bf16*  qkv     = (bf16*)base;
    bf16*  vemb    = (bf16*)(base + (size_t)M * 768 * 2);
    bf16*  attnout = (bf16*)(base + (size_t)M * 1024 * 2);
    float* stats1  = (float*)(base + (size_t)M * 1024 * 2 + (size_t)M * 256 * 2);
    float* stats2  = stats1 + 2 * M;
    bf16*  hbuf    = (bf16*)base;
    float* xres    = out;   // residual stream lives in d_out (fully rewritten each call)

    stats_kernel<<<M / 4, 256, 0, stream>>>(x, stats1);
    vemb_kernel<<<M, 256, 0, stream>>>(vote, vw1, vb1, vw2, vb2, vemb);

    dim3 gqkv(M / 64, 768 / 64);
    gemm_kernel<MODE_QKV><<<gqkv, 256, 0, stream>>>(x, wqkv, bqkv, stats1, g1, be1, vemb, qkv);

    attn_kernel<<<BT * HEADS, 256, 0, stream>>>(qkv, polar, rw1, rb1, rw2, rb2, tau, mask, attnout);

    dim3 gproj(M / 64, 256 / 64);
    gemm_kernel<MODE_PROJ><<<gproj, 256, 0, stream>>>(attnout, wproj, bproj, nullptr, nullptr, nullptr, x, xres);

    stats_kernel<<<M / 4, 256, 0, stream>>>(xres, stats2);

    dim3 gfc1(M / 64, 1024 / 64);
    gemm_kernel<MODE_FC1><<<gfc1, 256, 0, stream>>>(xres, fc1w, fc1b, stats2, g2, be2, nullptr, hbuf);

    dim3 gfc2(M / 64, 256 / 64);
    gemm_kernel<MODE_FC2><<<gfc2, 256, 0, stream>>>(hbuf, fc2w, fc2b, nullptr, nullptr, nullptr, xres, out);
}

// Round 4
// 525.045 us; speedup vs baseline: 3.8653x; 3.8653x over previous
//
#include <hip/hip_runtime.h>
#include <hip/hip_bf16.h>
#include <math.h>

using bf16 = __hip_bfloat16;
typedef __attribute__((ext_vector_type(8))) short short8;
typedef __attribute__((ext_vector_type(4))) float f32x4;
typedef unsigned int u32;

// ---------------- problem constants ----------------
constexpr int BB    = 4;
constexpr int Hh    = 112;
constexpr int Ww    = 112;
constexpr int C     = 256;
constexpr int L     = Hh * Ww;        // 12544
constexpr int HEADS = 8;
constexpr int WS    = 7;
constexpr int SHIFT = 3;
constexpr int HID   = 1024;
constexpr int HD    = 32;
constexpr int NWIN  = 49;
constexpr int NW    = 256;
constexpr int BT    = BB * NW;        // 1024 windows
constexpr int M     = BT * NWIN;      // 50176 tokens
constexpr float SCALE = 0.17677669529663687f;
constexpr float EPS   = 1e-5f;

// window-token r -> natural token index. Same map for gather and scatter.
__device__ __forceinline__ int src_row_idx(int r) {
    int b_ = r / NWIN;
    int n  = r - b_ * NWIN;
    int b  = b_ >> 8;
    int w  = b_ & 255;
    int wh = w >> 4, ww = w & 15;
    int i  = n / WS, j = n - i * WS;
    int hp = wh * WS + i, wp = ww * WS + j;
    int h  = hp + SHIFT; if (h >= Hh) h -= Hh;
    int wc = wp + SHIFT; if (wc >= Ww) wc -= Ww;
    return b * L + h * Ww + wc;
}

#define GL2LDS(g, l) __builtin_amdgcn_global_load_lds( \
    (const __attribute__((address_space(1))) u32*)(const void*)(g), \
    (__attribute__((address_space(3))) u32*)(void*)(l), 16, 0, 0)

// ---------------- per-token LN stats (mean, rstd) ----------------
__global__ __launch_bounds__(256)
void stats_kernel(const float* __restrict__ x, float* __restrict__ stats) {
    int wave = threadIdx.x >> 6, lane = threadIdx.x & 63;
    int tok  = blockIdx.x * 4 + wave;
    const float4 v = *(const float4*)&x[(size_t)tok * C + lane * 4];
    float s  = v.x + v.y + v.z + v.w;
    float s2 = v.x*v.x + v.y*v.y + v.z*v.z + v.w*v.w;
    #pragma unroll
    for (int o = 32; o > 0; o >>= 1) {
        s  += __shfl_down(s, o);
        s2 += __shfl_down(s2, o);
    }
    if (lane == 0) {
        float m   = s * (1.0f / C);
        float var = s2 * (1.0f / C) - m * m;
        stats[tok * 2]     = m;
        stats[tok * 2 + 1] = rsqrtf(var + EPS);
    }
}

// ---------------- f32 -> bf16 weight convert ----------------
__global__ __launch_bounds__(256)
void cvt_w(const float* __restrict__ in, bf16* __restrict__ o, int n4) {
    int i = blockIdx.x * 256 + threadIdx.x;
    if (i >= n4) return;
    float4 v = *(const float4*)&in[(size_t)i * 4];
    bf16 t4[4] = {__float2bfloat16(v.x), __float2bfloat16(v.y),
                  __float2bfloat16(v.z), __float2bfloat16(v.w)};
    *(uint2*)&o[(size_t)i * 4] = *(const uint2*)t4;
}

// ---------------- vote-embed MLP ----------------
__global__ __launch_bounds__(256)
void vemb_kernel(const float* __restrict__ vote,
                 const float* __restrict__ w1, const float* __restrict__ b1,
                 const float* __restrict__ w2, const float* __restrict__ b2,
                 bf16* __restrict__ vemb) {
    int r = blockIdx.x;
    int srow = src_row_idx(r);
    __shared__ float hv[16];
    __shared__ float vv[3];
    int t = threadIdx.x;
    if (t < 3) vv[t] = vote[(size_t)srow * 3 + t];
    __syncthreads();
    if (t < 16)
        hv[t] = fmaxf(w1[t*3]*vv[0] + w1[t*3+1]*vv[1] + w1[t*3+2]*vv[2] + b1[t], 0.f);
    __syncthreads();
    float acc = b2[t];
    #pragma unroll
    for (int o = 0; o < 16; ++o) acc += hv[o] * w2[t * 16 + o];
    vemb[(size_t)r * C + t] = __float2bfloat16(acc);
}

// ---------------- MFMA GEMM: out = A @ Wb^T + fused LN / epilogue ----------
// 128x128 tile, BK=64, 4 waves x (64x64 output via 4x4 16x16x32 frags).
// LDS tiles [128 rows][64 bf16], byte ^= ((row&7)<<4) XOR swizzle.
// A reg-staged (optionally f32+LN+gather fused); B via global_load_lds with
// inverse-swizzled per-lane SOURCE (linear dest, rule #21).
enum { MODE_QKV = 0, MODE_PROJ = 1, MODE_FC1 = 2, MODE_FC2 = 3 };

template <int MODE>
__global__ __launch_bounds__(256)
void mfma_gemm(const void* __restrict__ Asrc_, const bf16* __restrict__ Wb,
               const float* __restrict__ bias, const float* __restrict__ stats,
               const float* __restrict__ gamma, const float* __restrict__ beta,
               const bf16* __restrict__ vemb, const float* __restrict__ resid,
               void* __restrict__ outp) {
    constexpr int  K  = (MODE == MODE_FC2) ? 1024 : 256;
    constexpr bool LN = (MODE == MODE_QKV) || (MODE == MODE_FC1);  // A is f32+LN
    __shared__ __align__(16) char lds[32768];
    char* ldsA = lds;
    char* ldsB = lds + 16384;

    const int tid  = threadIdx.x;
    const int lane = tid & 63;
    const int wid  = tid >> 6;
    const int wr   = wid >> 1, wc = wid & 1;
    const int lrow = lane & 15, lk = lane >> 4;
    const int mBase = blockIdx.x * 128, nBase = blockIdx.y * 128;

    const int s_sub = tid >> 3;                       // 0..31: row within rep
    const int chunk = tid & 7;                        // 16B chunk within row
    const int s_dst = (chunk * 16) ^ ((s_sub & 7) << 4);  // swizzled byte in row
    const char* bSrc = (const char*)(Wb + (size_t)(nBase + s_sub) * K) + s_dst;

    int arow[4]; float amean[4], arstd[4];
    #pragma unroll
    for (int r = 0; r < 4; ++r) {
        int row  = mBase + r * 32 + s_sub;
        int srow = (MODE == MODE_QKV) ? src_row_idx(row) : row;
        arow[r] = srow;
        if constexpr (LN) {
            amean[r] = stats[srow * 2];
            arstd[r] = stats[srow * 2 + 1];
        }
    }

    f32x4 acc[4][4] = {};

    for (int t = 0; t < K / 64; ++t) {
        const int k0 = t * 64;
        if (t) __syncthreads();               // prior compute done before overwrite
        #pragma unroll
        for (int r = 0; r < 4; ++r)           // B: DMA, linear dest = swizzled data
            GL2LDS(bSrc + (size_t)r * 64 * K + (size_t)t * 128,
                   ldsB + r * 4096 + wid * 1024);
        float4 g0, g1v, b0, b1v;
        if constexpr (LN) {
            const int kk = k0 + chunk * 8;
            g0  = *(const float4*)&gamma[kk];
            g1v = *(const float4*)&gamma[kk + 4];
            b0  = *(const float4*)&beta[kk];
            b1v = *(const float4*)&beta[kk + 4];
        }
        #pragma unroll
        for (int r = 0; r < 4; ++r) {         // A: reg-staged (+LN fused)
            short8 av;
            if constexpr (LN) {
                const float* src = (const float*)Asrc_ + (size_t)arow[r] * K + k0 + chunk * 8;
                float4 v0 = *(const float4*)src;
                float4 v1 = *(const float4*)(src + 4);
                float m = amean[r], sd = arstd[r];
                bf16 tb[8];
                tb[0] = __float2bfloat16((v0.x - m) * sd * g0.x  + b0.x);
                tb[1] = __float2bfloat16((v0.y - m) * sd * g0.y  + b0.y);
                tb[2] = __float2bfloat16((v0.z - m) * sd * g0.z  + b0.z);
                tb[3] = __float2bfloat16((v0.w - m) * sd * g0.w  + b0.w);
                tb[4] = __float2bfloat16((v1.x - m) * sd * g1v.x + b1v.x);
                tb[5] = __float2bfloat16((v1.y - m) * sd * g1v.y + b1v.y);
                tb[6] = __float2bfloat16((v1.z - m) * sd * g1v.z + b1v.z);
                tb[7] = __float2bfloat16((v1.w - m) * sd * g1v.w + b1v.w);
                av = *(const short8*)tb;
            } else {
                av = *(const short8*)((const bf16*)Asrc_ + (size_t)arow[r] * K + k0 + chunk * 8);
            }
            *(short8*)(ldsA + (r * 32 + s_sub) * 128 + s_dst) = av;
        }
        __syncthreads();
        const int sw = (lrow & 7) << 4;
        #pragma unroll
        for (int ks = 0; ks < 2; ++ks) {      // 2 x K=32 slices per 64-elem step
            const int kbl = (ks * 64 + lk * 16) ^ sw;
            short8 af[4], bfr[4];
            #pragma unroll
            for (int q = 0; q < 4; ++q) {
                af[q]  = *(const short8*)(ldsA + (wr * 64 + q * 16 + lrow) * 128 + kbl);
                bfr[q] = *(const short8*)(ldsB + (wc * 64 + q * 16 + lrow) * 128 + kbl);
            }
            #pragma unroll
            for (int mi = 0; mi < 4; ++mi)
                #pragma unroll
                for (int ni = 0; ni < 4; ++ni)
                    acc[mi][ni] = __builtin_amdgcn_mfma_f32_16x16x32_bf16(
                        af[mi], bfr[ni], acc[mi][ni], 0, 0, 0);
        }
    }

    // epilogue: lane holds D[(lane>>4)*4+i][lane&15] of each 16x16 frag
    const int cB = nBase + wc * 64 + lrow;
    const int rB = mBase + wr * 64 + lk * 4;
    #pragma unroll
    for (int ni = 0; ni < 4; ++ni) {
        const int c = cB + ni * 16;
        const float bs = bias[c];
        #pragma unroll
        for (int mi = 0; mi < 4; ++mi) {
            #pragma unroll
            for (int i = 0; i < 4; ++i) {
                const int r = rB + mi * 16 + i;
                float v = acc[mi][ni][i] + bs;
                if constexpr (MODE == MODE_QKV) {
                    float ve = __bfloat162float(vemb[(size_t)r * 256 + (c & 255)]);
                    v += (c >= 512) ? 2.f * ve : ve;   // v-path carries qkv2 + 2*vemb
                    ((bf16*)outp)[(size_t)r * 768 + c] = __float2bfloat16(v);
                } else if constexpr (MODE == MODE_PROJ) {
                    int dst = src_row_idx(r);
                    ((float*)outp)[(size_t)dst * 256 + c] =
                        resid[(size_t)dst * 256 + c] + v;
                } else if constexpr (MODE == MODE_FC1) {
                    float gl = 0.5f * v * (1.f + erff(v * 0.70710678118f));
                    ((bf16*)outp)[(size_t)r * 1024 + c] = __float2bfloat16(gl);
                } else {  // FC2: final residual add, f32 out
                    ((float*)outp)[(size_t)r * 256 + c] =
                        resid[(size_t)r * 256 + c] + v;
                }
            }
        }
    }
}

// ---------------- per-(window, head) cosine attention ----------------
__global__ __launch_bounds__(256)
void attn_kernel(const bf16* __restrict__ qkv, const float* __restrict__ polar,
                 const float* __restrict__ rw1, const float* __restrict__ rb1,
                 const float* __restrict__ rw2, const float* __restrict__ rb2,
                 const float* __restrict__ tau, const float* __restrict__ mask,
                 bf16* __restrict__ outp) {
    int b_   = blockIdx.x >> 3;
    int head = blockIdx.x & 7;
    int t    = threadIdx.x;

    constexpr int SP = 53;
    __shared__ float qsT[HD * SP], ksT[HD * SP], vsT[HD * SP];
    __shared__ float at[NWIN * 50];
    __shared__ float pwx[NWIN], pwy[NWIN];
    __shared__ float qn[NWIN], kn[NWIN];
    __shared__ float cw1[32], cb1[16], cw2[16];

    for (int idx = t; idx < NWIN * HD; idx += 256) {
        int n = idx >> 5, d = idx & 31;
        size_t row = ((size_t)b_ * NWIN + n) * 768 + head * HD + d;
        qsT[d * SP + n] = __bfloat162float(qkv[row]);
        ksT[d * SP + n] = __bfloat162float(qkv[row + 256]);
        vsT[d * SP + n] = __bfloat162float(qkv[row + 512]);
    }
    if (t < 98) {
        int n = t >> 1, cix = t & 1;
        int srow = src_row_idx(b_ * NWIN + n);
        float v = polar[(size_t)srow * 2 + cix];
        if (cix) pwy[n] = v; else pwx[n] = v;
    }
    if (t >= 128 && t < 160) cw1[t - 128] = rw1[t - 128];
    else if (t >= 160 && t < 176) cb1[t - 160] = rb1[t - 160];
    else if (t >= 176 && t < 192) cw2[t - 176] = rw2[head * 16 + (t - 176)];
    __syncthreads();

    if (t < NWIN) {
        float s = 0;
        #pragma unroll
        for (int d = 0; d < HD; ++d) { float v = qsT[d * SP + t]; s += v * v; }
        qn[t] = sqrtf(s);
    } else if (t >= 64 && t < 64 + NWIN) {
        int n = t - 64; float s = 0;
        #pragma unroll
        for (int d = 0; d < HD; ++d) { float v = ksT[d * SP + n]; s += v * v; }
        kn[n] = sqrtf(s);
    }
    __syncthreads();

    float tauc = fmaxf(tau[head], 0.01f);
    float rb2h = rb2[head];
    const float* mrow = mask + (size_t)(b_ & 255) * NWIN * NWIN;

    for (int e = t; e < NWIN * NWIN; e += 256) {
        int n = e / NWIN, m = e - n * NWIN;
        float dot = 0;
        #pragma unroll
        for (int d = 0; d < HD; ++d)
            dot = fmaf(qsT[d * SP + n], ksT[d * SP + m], dot);
        float a = dot * SCALE / fmaxf(qn[n] * kn[m], 1e-6f) / tauc;
        float dx = pwx[n] - pwx[m], dy = pwy[n] - pwy[m];
        float racc = rb2h;
        #pragma unroll
        for (int o = 0; o < 16; ++o)
            racc = fmaf(fmaxf(fmaf(cw1[2*o], dx, fmaf(cw1[2*o+1], dy, cb1[o])), 0.f),
                        cw2[o], racc);
        at[n * 50 + m] = a + racc + mrow[e];
    }
    __syncthreads();

    if (t < NWIN) {
        float mx = -1e30f;
        for (int m = 0; m < NWIN; ++m) mx = fmaxf(mx, at[t * 50 + m]);
        float s = 0;
        for (int m = 0; m < NWIN; ++m) {
            float ev = expf(at[t * 50 + m] - mx);
            at[t * 50 + m] = ev; s += ev;
        }
        float inv = 1.f / s;
        for (int m = 0; m < NWIN; ++m) at[t * 50 + m] *= inv;
    }
    __syncthreads();

    for (int e = t; e < NWIN * HD; e += 256) {
        int n = e >> 5, d = e & 31;
        float acc = 0;
        #pragma unroll
        for (int m = 0; m < NWIN; ++m)
            acc = fmaf(at[n * 50 + m], vsT[d * SP + m], acc);
        outp[((size_t)b_ * NWIN + n) * C + head * HD + d] = __float2bfloat16(acc);
    }
}

// ---------------- launch ----------------
extern "C" void kernel_launch(void* const* d_in, const int* in_sizes, int n_in,
                              void* d_out, int out_size, void* d_ws, size_t ws_size,
                              hipStream_t stream) {
    const float* x     = (const float*)d_in[0];
    const float* mask  = (const float*)d_in[1];
    const float* polar = (const float*)d_in[2];
    const float* vote  = (const float*)d_in[3];
    const float* g1    = (const float*)d_in[4];
    const float* be1   = (const float*)d_in[5];
    const float* wqkv  = (const float*)d_in[6];
    const float* bqkv  = (const float*)d_in[7];
    const float* wproj = (const float*)d_in[8];
    const float* bproj = (const float*)d_in[9];
    const float* tau   = (const float*)d_in[10];
    const float* rw1   = (const float*)d_in[11];
    const float* rb1   = (const float*)d_in[12];
    const float* rw2   = (const float*)d_in[13];
    const float* rb2   = (const float*)d_in[14];
    const float* vw1   = (const float*)d_in[15];
    const float* vb1   = (const float*)d_in[16];
    const float* vw2   = (const float*)d_in[17];
    const float* vb2   = (const float*)d_in[18];
    const float* g2    = (const float*)d_in[19];
    const float* be2   = (const float*)d_in[20];
    const float* fc1w  = (const float*)d_in[21];
    const float* fc1b  = (const float*)d_in[22];
    const float* fc2w  = (const float*)d_in[23];
    const float* fc2b  = (const float*)d_in[24];
    float* out = (float*)d_out;

    // workspace (bytes), total 105,136,128 (~100.3 MB):
    //   qkv     [0,          77,070,336)  bf16 [M][768]   dead after attn
    //   vemb    [77,070,336, 102,760,448) bf16 [M][256]   dead after QKV
    //   attnout overlays vemb              bf16 [M][256]  dead after proj
    //   hbuf    [0,         102,760,448)  bf16 [M][1024]  overlays qkv+attnout
    //   weights [102,760,448, 104,333,312) bf16
    //   stats1/stats2 f32 [M][2] at [104,333,312, 105,136,128)
    char* base = (char*)d_ws;
    bf16*  qkv     = (bf16*)base;
    bf16*  vemb    = (bf16*)(base + 77070336);
    bf16*  attnout = (bf16*)(base + 77070336);
    bf16*  hbuf    = (bf16*)base;
    bf16*  wqkvb   = (bf16*)(base + 102760448);
    bf16*  wprojb  = wqkvb + 768 * 256;
    bf16*  fc1wb   = wprojb + 256 * 256;
    bf16*  fc2wb   = fc1wb + 1024 * 256;
    float* stats1  = (float*)(base + 104333312);
    float* stats2  = stats1 + 2 * M;

    cvt_w<<<192, 256, 0, stream>>>(wqkv, wqkvb, 768*256/4);
    cvt_w<<<64,  256, 0, stream>>>(wproj, wprojb, 256*256/4);
    cvt_w<<<256, 256, 0, stream>>>(fc1w, fc1wb, 1024*256/4);
    cvt_w<<<256, 256, 0, stream>>>(fc2w, fc2wb, 256*1024/4);

    stats_kernel<<<M / 4, 256, 0, stream>>>(x, stats1);
    vemb_kernel<<<M, 256, 0, stream>>>(vote, vw1, vb1, vw2, vb2, vemb);

    dim3 gqkv(M / 128, 768 / 128);
    mfma_gemm<MODE_QKV><<<gqkv, 256, 0, stream>>>(x, wqkvb, bqkv, stats1, g1, be1, vemb, nullptr, qkv);

    attn_kernel<<<BT * HEADS, 256, 0, stream>>>(qkv, polar, rw1, rb1, rw2, rb2, tau, mask, attnout);

    dim3 gproj(M / 128, 256 / 128);
    mfma_gemm<MODE_PROJ><<<gproj, 256, 0, stream>>>(attnout, wprojb, bproj, nullptr, nullptr, nullptr, nullptr, x, out);

    stats_kernel<<<M / 4, 256, 0, stream>>>(out, stats2);

    dim3 gfc1(M / 128, 1024 / 128);
    mfma_gemm<MODE_FC1><<<gfc1, 256, 0, stream>>>(out, fc1wb, fc1b, stats2, g2, be2, nullptr, nullptr, hbuf);

    dim3 gfc2(M / 128, 256 / 128);
    mfma_gemm<MODE_FC2><<<gfc2, 256, 0, stream>>>(hbuf, fc2wb, fc2b, nullptr, nullptr, nullptr, nullptr, out, out);
}

// Round 6
// 466.635 us; speedup vs baseline: 4.3491x; 1.1252x over previous
//
#include <hip/hip_runtime.h>
#include <hip/hip_bf16.h>
#include <math.h>

using bf16 = __hip_bfloat16;
typedef __attribute__((ext_vector_type(8))) short short8;
typedef __attribute__((ext_vector_type(4))) float f32x4;
typedef unsigned int u32;

// ---------------- problem constants ----------------
constexpr int BB    = 4;
constexpr int Hh    = 112;
constexpr int Ww    = 112;
constexpr int C     = 256;
constexpr int L     = Hh * Ww;        // 12544
constexpr int HEADS = 8;
constexpr int WS    = 7;
constexpr int SHIFT = 3;
constexpr int HID   = 1024;
constexpr int HD    = 32;
constexpr int NWIN  = 49;
constexpr int NW    = 256;
constexpr int BT    = BB * NW;        // 1024 windows
constexpr int M     = BT * NWIN;      // 50176 tokens
constexpr float SCALE = 0.17677669529663687f;
constexpr float EPS   = 1e-5f;

// window-token r -> natural token index. Same map for gather and scatter.
__device__ __forceinline__ int src_row_idx(int r) {
    int b_ = r / NWIN;
    int n  = r - b_ * NWIN;
    int b  = b_ >> 8;
    int w  = b_ & 255;
    int wh = w >> 4, ww = w & 15;
    int i  = n / WS, j = n - i * WS;
    int hp = wh * WS + i, wp = ww * WS + j;
    int h  = hp + SHIFT; if (h >= Hh) h -= Hh;
    int wc = wp + SHIFT; if (wc >= Ww) wc -= Ww;
    return b * L + h * Ww + wc;
}

__device__ __forceinline__ float bf2f(short s) {
    u32 u = ((u32)(unsigned short)s) << 16;
    float f; __builtin_memcpy(&f, &u, 4); return f;
}

#define GL2LDS(g, l) __builtin_amdgcn_global_load_lds( \
    (const __attribute__((address_space(1))) u32*)(const void*)(g), \
    (__attribute__((address_space(3))) u32*)(void*)(l), 16, 0, 0)

// ---------------- per-token LN stats (mean, rstd) ----------------
__global__ __launch_bounds__(256)
void stats_kernel(const float* __restrict__ x, float* __restrict__ stats) {
    int wave = threadIdx.x >> 6, lane = threadIdx.x & 63;
    int tok  = blockIdx.x * 4 + wave;
    const float4 v = *(const float4*)&x[(size_t)tok * C + lane * 4];
    float s  = v.x + v.y + v.z + v.w;
    float s2 = v.x*v.x + v.y*v.y + v.z*v.z + v.w*v.w;
    #pragma unroll
    for (int o = 32; o > 0; o >>= 1) {
        s  += __shfl_down(s, o);
        s2 += __shfl_down(s2, o);
    }
    if (lane == 0) {
        float m   = s * (1.0f / C);
        float var = s2 * (1.0f / C) - m * m;
        stats[tok * 2]     = m;
        stats[tok * 2 + 1] = rsqrtf(var + EPS);
    }
}

// ---------------- f32 -> bf16 weight convert ----------------
__global__ __launch_bounds__(256)
void cvt_w(const float* __restrict__ in, bf16* __restrict__ o, int n4) {
    int i = blockIdx.x * 256 + threadIdx.x;
    if (i >= n4) return;
    float4 v = *(const float4*)&in[(size_t)i * 4];
    bf16 t4[4] = {__float2bfloat16(v.x), __float2bfloat16(v.y),
                  __float2bfloat16(v.z), __float2bfloat16(v.w)};
    *(uint2*)&o[(size_t)i * 4] = *(const uint2*)t4;
}

// ---------------- vote-embed MLP (one wave per token) ----------------
__global__ __launch_bounds__(256)
void vemb_kernel(const float* __restrict__ vote,
                 const float* __restrict__ w1, const float* __restrict__ b1,
                 const float* __restrict__ w2, const float* __restrict__ b2,
                 bf16* __restrict__ vemb) {
    int r = blockIdx.x * 4 + (threadIdx.x >> 6);
    int lane = threadIdx.x & 63;
    int srow = src_row_idx(r);
    float v0 = vote[(size_t)srow * 3];
    float v1 = vote[(size_t)srow * 3 + 1];
    float v2c = vote[(size_t)srow * 3 + 2];
    float hid[16];
    #pragma unroll
    for (int o = 0; o < 16; ++o)
        hid[o] = fmaxf(w1[o*3]*v0 + w1[o*3+1]*v1 + w1[o*3+2]*v2c + b1[o], 0.f);
    bf16 t4[4];
    #pragma unroll
    for (int j = 0; j < 4; ++j) {
        int c = lane * 4 + j;
        float a = b2[c];
        #pragma unroll
        for (int o = 0; o < 16; ++o) a += hid[o] * w2[c * 16 + o];
        t4[j] = __float2bfloat16(a);
    }
    *(uint2*)&vemb[(size_t)r * C + lane * 4] = *(const uint2*)t4;
}

// ---------------- MFMA GEMM (unchanged from R4) ----------
enum { MODE_QKV = 0, MODE_PROJ = 1, MODE_FC1 = 2, MODE_FC2 = 3 };

template <int MODE>
__global__ __launch_bounds__(256)
void mfma_gemm(const void* __restrict__ Asrc_, const bf16* __restrict__ Wb,
               const float* __restrict__ bias, const float* __restrict__ stats,
               const float* __restrict__ gamma, const float* __restrict__ beta,
               const bf16* __restrict__ vemb, const float* __restrict__ resid,
               void* __restrict__ outp) {
    constexpr int  K  = (MODE == MODE_FC2) ? 1024 : 256;
    constexpr bool LN = (MODE == MODE_QKV) || (MODE == MODE_FC1);
    __shared__ __align__(16) char lds[32768];
    char* ldsA = lds;
    char* ldsB = lds + 16384;

    const int tid  = threadIdx.x;
    const int lane = tid & 63;
    const int wid  = tid >> 6;
    const int wr   = wid >> 1, wc = wid & 1;
    const int lrow = lane & 15, lk = lane >> 4;
    const int mBase = blockIdx.x * 128, nBase = blockIdx.y * 128;

    const int s_sub = tid >> 3;
    const int chunk = tid & 7;
    const int s_dst = (chunk * 16) ^ ((s_sub & 7) << 4);
    const char* bSrc = (const char*)(Wb + (size_t)(nBase + s_sub) * K) + s_dst;

    int arow[4]; float amean[4], arstd[4];
    #pragma unroll
    for (int r = 0; r < 4; ++r) {
        int row  = mBase + r * 32 + s_sub;
        int srow = (MODE == MODE_QKV) ? src_row_idx(row) : row;
        arow[r] = srow;
        if constexpr (LN) {
            amean[r] = stats[srow * 2];
            arstd[r] = stats[srow * 2 + 1];
        }
    }

    f32x4 acc[4][4] = {};

    for (int t = 0; t < K / 64; ++t) {
        const int k0 = t * 64;
        if (t) __syncthreads();
        #pragma unroll
        for (int r = 0; r < 4; ++r)
            GL2LDS(bSrc + (size_t)r * 64 * K + (size_t)t * 128,
                   ldsB + r * 4096 + wid * 1024);
        float4 g0, g1v, b0, b1v;
        if constexpr (LN) {
            const int kk = k0 + chunk * 8;
            g0  = *(const float4*)&gamma[kk];
            g1v = *(const float4*)&gamma[kk + 4];
            b0  = *(const float4*)&beta[kk];
            b1v = *(const float4*)&beta[kk + 4];
        }
        #pragma unroll
        for (int r = 0; r < 4; ++r) {
            short8 av;
            if constexpr (LN) {
                const float* src = (const float*)Asrc_ + (size_t)arow[r] * K + k0 + chunk * 8;
                float4 v0 = *(const float4*)src;
                float4 v1 = *(const float4*)(src + 4);
                float m = amean[r], sd = arstd[r];
                bf16 tb[8];
                tb[0] = __float2bfloat16((v0.x - m) * sd * g0.x  + b0.x);
                tb[1] = __float2bfloat16((v0.y - m) * sd * g0.y  + b0.y);
                tb[2] = __float2bfloat16((v0.z - m) * sd * g0.z  + b0.z);
                tb[3] = __float2bfloat16((v0.w - m) * sd * g0.w  + b0.w);
                tb[4] = __float2bfloat16((v1.x - m) * sd * g1v.x + b1v.x);
                tb[5] = __float2bfloat16((v1.y - m) * sd * g1v.y + b1v.y);
                tb[6] = __float2bfloat16((v1.z - m) * sd * g1v.z + b1v.z);
                tb[7] = __float2bfloat16((v1.w - m) * sd * g1v.w + b1v.w);
                av = *(const short8*)tb;
            } else {
                av = *(const short8*)((const bf16*)Asrc_ + (size_t)arow[r] * K + k0 + chunk * 8);
            }
            *(short8*)(ldsA + (r * 32 + s_sub) * 128 + s_dst) = av;
        }
        __syncthreads();
        const int sw = (lrow & 7) << 4;
        #pragma unroll
        for (int ks = 0; ks < 2; ++ks) {
            const int kbl = (ks * 64 + lk * 16) ^ sw;
            short8 af[4], bfr[4];
            #pragma unroll
            for (int q = 0; q < 4; ++q) {
                af[q]  = *(const short8*)(ldsA + (wr * 64 + q * 16 + lrow) * 128 + kbl);
                bfr[q] = *(const short8*)(ldsB + (wc * 64 + q * 16 + lrow) * 128 + kbl);
            }
            #pragma unroll
            for (int mi = 0; mi < 4; ++mi)
                #pragma unroll
                for (int ni = 0; ni < 4; ++ni)
                    acc[mi][ni] = __builtin_amdgcn_mfma_f32_16x16x32_bf16(
                        af[mi], bfr[ni], acc[mi][ni], 0, 0, 0);
        }
    }

    const int cB = nBase + wc * 64 + lrow;
    const int rB = mBase + wr * 64 + lk * 4;
    #pragma unroll
    for (int ni = 0; ni < 4; ++ni) {
        const int c = cB + ni * 16;
        const float bs = bias[c];
        #pragma unroll
        for (int mi = 0; mi < 4; ++mi) {
            #pragma unroll
            for (int i = 0; i < 4; ++i) {
                const int r = rB + mi * 16 + i;
                float v = acc[mi][ni][i] + bs;
                if constexpr (MODE == MODE_QKV) {
                    float ve = __bfloat162float(vemb[(size_t)r * 256 + (c & 255)]);
                    v += (c >= 512) ? 2.f * ve : ve;
                    ((bf16*)outp)[(size_t)r * 768 + c] = __float2bfloat16(v);
                } else if constexpr (MODE == MODE_PROJ) {
                    int dst = src_row_idx(r);
                    ((float*)outp)[(size_t)dst * 256 + c] =
                        resid[(size_t)dst * 256 + c] + v;
                } else if constexpr (MODE == MODE_FC1) {
                    float gl = 0.5f * v * (1.f + erff(v * 0.70710678118f));
                    ((bf16*)outp)[(size_t)r * 1024 + c] = __float2bfloat16(gl);
                } else {
                    ((float*)outp)[(size_t)r * 256 + c] =
                        resid[(size_t)r * 256 + c] + v;
                }
            }
        }
    }
}

// ---------------- per-window attention: MFMA + RPE dedup ----------------
// One block per window (256 thr = 4 waves). Heads in 2 groups of 4:
// phase1 computes rpe+mask for 4 heads into LDS (hidden MLP computed once
// per (n,m)); then per head: MFMA QK^T (rows padded 49->64), cosine
// normalize + rpe, wave-parallel softmax, P->LDS, MFMA PV, write attnout.
__global__ __launch_bounds__(256)
void attn_kernel(const bf16* __restrict__ qkv, const float* __restrict__ polar,
                 const float* __restrict__ rw1, const float* __restrict__ rb1,
                 const float* __restrict__ rw2, const float* __restrict__ rb2,
                 const float* __restrict__ tau, const float* __restrict__ mask,
                 bf16* __restrict__ outp) {
    const int w  = blockIdx.x;
    const int wl = w & 255;
    const int t  = threadIdx.x;
    const int lane = t & 63, wid = t >> 6;
    const int l15 = lane & 15, q4 = lane >> 4;
    const size_t wbase = (size_t)w * NWIN;

    __shared__ float pwx[NWIN], pwy[NWIN];
    __shared__ float rqn[8][64], rkn[8][64];     // reciprocal norms (valid n<49)
    __shared__ float cw1s[32], cb1s[16], cw2s[8][16], rb2s[8], scts[8];
    __shared__ bf16  rpem[4][2401];
    __shared__ short P_lds[64][72];              // bf16 bits; stride 72 rows
    __shared__ short VT[32][72];                 // bf16 bits

    // zero VT once: pad cols m>=49 must stay 0.
    for (int i = t; i < 32 * 72; i += 256) ((short*)VT)[i] = 0;

    for (int u = t; u < 98; u += 256) {
        int n = u >> 1, cix = u & 1;
        int srow = src_row_idx(w * NWIN + n);
        float v = polar[(size_t)srow * 2 + cix];
        if (cix) pwy[n] = v; else pwx[n] = v;
    }
    if (t < 128) cw2s[t >> 4][t & 15] = rw2[t];
    else if (t < 160) cw1s[t - 128] = rw1[t - 128];
    else if (t < 176) cb1s[t - 160] = rb1[t - 160];
    else if (t < 184) rb2s[t - 176] = rb2[t - 176];
    else if (t < 192) scts[t - 184] = SCALE / fmaxf(tau[t - 184], 0.01f);

    // reciprocal q/k norms for all heads
    for (int idx = t; idx < 8 * NWIN; idx += 256) {
        int h = idx / NWIN, n = idx - h * NWIN;
        const bf16* qp = qkv + (wbase + n) * 768 + h * 32;
        float sq = 0, sk = 0;
        #pragma unroll
        for (int c = 0; c < 4; ++c) {
            short8 qv = *(const short8*)(qp + c * 8);
            short8 kv = *(const short8*)(qp + 256 + c * 8);
            #pragma unroll
            for (int j = 0; j < 8; ++j) {
                float qf = bf2f(qv[j]); sq += qf * qf;
                float kf = bf2f(kv[j]); sk += kf * kf;
            }
        }
        rqn[h][n] = rsqrtf(sq);     // 1/max(qn*kn,1e-6) == min(rq*rk,1e6)
        rkn[h][n] = rsqrtf(sk);
    }

    for (int g = 0; g < 2; ++g) {
        __syncthreads();   // prior group's rpem reads + VT/P reads done
        // ---- phase 1: rpe hidden once, project 4 heads, +mask -> LDS ----
        for (int e = t; e < NWIN * NWIN; e += 256) {
            int n = e / NWIN, m = e - n * NWIN;
            float dx = pwx[n] - pwx[m], dy = pwy[n] - pwy[m];
            float hid[16];
            #pragma unroll
            for (int o = 0; o < 16; ++o)
                hid[o] = fmaxf(fmaf(cw1s[2*o], dx, fmaf(cw1s[2*o+1], dy, cb1s[o])), 0.f);
            float mv = mask[(size_t)wl * NWIN * NWIN + e];
            #pragma unroll
            for (int hh = 0; hh < 4; ++hh) {
                int h = 4 * g + hh;
                float a = rb2s[h] + mv;
                #pragma unroll
                for (int o = 0; o < 16; ++o) a = fmaf(hid[o], cw2s[h][o], a);
                rpem[hh][e] = __float2bfloat16(a);
            }
        }

        for (int hh = 0; hh < 4; ++hh) {
            const int h = 4 * g + hh;
            __syncthreads();   // prev head's P/VT reads done; rpem ready (g-loop)

            // stage V transposed: VT[d][m] (m<49), raw bf16 bits
            {
                int n = t >> 2, ck = t & 3;
                if (n < NWIN) {
                    short8 vv8 = *(const short8*)(qkv + (wbase + n) * 768 + 512 + h * 32 + ck * 8);
                    #pragma unroll
                    for (int j = 0; j < 8; ++j) VT[ck * 8 + j][n] = vv8[j];
                }
            }

            // Q/K fragments straight from global (pad rows/cols -> 0)
            short8 aq = {0,0,0,0,0,0,0,0};
            {
                int n = wid * 16 + l15;
                if (n < NWIN)
                    aq = *(const short8*)(qkv + (wbase + n) * 768 + h * 32 + q4 * 8);
            }
            short8 bk[4];
            #pragma unroll
            for (int c = 0; c < 4; ++c) {
                int m = c * 16 + l15;
                short8 z = {0,0,0,0,0,0,0,0};
                bk[c] = (m < NWIN)
                    ? *(const short8*)(qkv + (wbase + m) * 768 + 256 + h * 32 + q4 * 8)
                    : z;
            }
            f32x4 s[4] = {};
            #pragma unroll
            for (int c = 0; c < 4; ++c)
                s[c] = __builtin_amdgcn_mfma_f32_16x16x32_bf16(aq, bk[c], s[c], 0, 0, 0);

            // cosine normalize + rpe ; pad -> -1e30
            const float sct = scts[h];
            float vv[4][4];
            #pragma unroll
            for (int c = 0; c < 4; ++c) {
                int m = c * 16 + l15;
                #pragma unroll
                for (int i = 0; i < 4; ++i) {
                    int n = wid * 16 + q4 * 4 + i;
                    float val = -1e30f;
                    if (n < NWIN && m < NWIN) {
                        float rr = fminf(rqn[h][n] * rkn[h][m], 1e6f);
                        val = s[c][i] * sct * rr + bf2f(*(short*)&rpem[hh][n * NWIN + m]);
                    }
                    vv[c][i] = val;
                }
            }

            // wave-parallel softmax (row spread over 16 lanes x 4 col-tiles)
            #pragma unroll
            for (int i = 0; i < 4; ++i) {
                float mx = fmaxf(fmaxf(vv[0][i], vv[1][i]), fmaxf(vv[2][i], vv[3][i]));
                #pragma unroll
                for (int d = 1; d < 16; d <<= 1) mx = fmaxf(mx, __shfl_xor(mx, d));
                float sum = 0;
                #pragma unroll
                for (int c = 0; c < 4; ++c) {
                    float ev = __expf(vv[c][i] - mx);
                    vv[c][i] = ev; sum += ev;
                }
                #pragma unroll
                for (int d = 1; d < 16; d <<= 1) sum += __shfl_xor(sum, d);
                float inv = 1.0f / sum;
                #pragma unroll
                for (int c = 0; c < 4; ++c) vv[c][i] *= inv;
            }

            // P -> LDS (D-layout write, bf16 bits)
            #pragma unroll
            for (int c = 0; c < 4; ++c)
                #pragma unroll
                for (int i = 0; i < 4; ++i) {
                    bf16 pb = __float2bfloat16(vv[c][i]);
                    short ps; __builtin_memcpy(&ps, &pb, 2);
                    P_lds[wid * 16 + q4 * 4 + i][c * 16 + l15] = ps;
                }

            __syncthreads();   // P + VT visible

            // PV: O[n][d] = sum_m P[n][m] * V[m][d]
            short8 pa[2];
            #pragma unroll
            for (int ks = 0; ks < 2; ++ks)
                pa[ks] = *(const short8*)&P_lds[wid * 16 + l15][ks * 32 + q4 * 8];
            f32x4 o[2] = {};
            #pragma unroll
            for (int ct = 0; ct < 2; ++ct) {
                #pragma unroll
                for (int ks = 0; ks < 2; ++ks) {
                    short8 vb = *(const short8*)&VT[ct * 16 + l15][ks * 32 + q4 * 8];
                    o[ct] = __builtin_amdgcn_mfma_f32_16x16x32_bf16(pa[ks], vb, o[ct], 0, 0, 0);
                }
            }
            #pragma unroll
            for (int ct = 0; ct < 2; ++ct)
                #pragma unroll
                for (int i = 0; i < 4; ++i) {
                    int n = wid * 16 + q4 * 4 + i;
                    if (n < NWIN)
                        outp[(wbase + n) * 256 + h * 32 + ct * 16 + l15] =
                            __float2bfloat16(o[ct][i]);
                }
        }
    }
}

// ---------------- launch ----------------
extern "C" void kernel_launch(void* const* d_in, const int* in_sizes, int n_in,
                              void* d_out, int out_size, void* d_ws, size_t ws_size,
                              hipStream_t stream) {
    const float* x     = (const float*)d_in[0];
    const float* mask  = (const float*)d_in[1];
    const float* polar = (const float*)d_in[2];
    const float* vote  = (const float*)d_in[3];
    const float* g1    = (const float*)d_in[4];
    const float* be1   = (const float*)d_in[5];
    const float* wqkv  = (const float*)d_in[6];
    const float* bqkv  = (const float*)d_in[7];
    const float* wproj = (const float*)d_in[8];
    const float* bproj = (const float*)d_in[9];
    const float* tau   = (const float*)d_in[10];
    const float* rw1   = (const float*)d_in[11];
    const float* rb1   = (const float*)d_in[12];
    const float* rw2   = (const float*)d_in[13];
    const float* rb2   = (const float*)d_in[14];
    const float* vw1   = (const float*)d_in[15];
    const float* vb1   = (const float*)d_in[16];
    const float* vw2   = (const float*)d_in[17];
    const float* vb2   = (const float*)d_in[18];
    const float* g2    = (const float*)d_in[19];
    const float* be2   = (const float*)d_in[20];
    const float* fc1w  = (const float*)d_in[21];
    const float* fc1b  = (const float*)d_in[22];
    const float* fc2w  = (const float*)d_in[23];
    const float* fc2b  = (const float*)d_in[24];
    float* out = (float*)d_out;

    // workspace (bytes), total ~105.1 MB (same plan as R4)
    char* base = (char*)d_ws;
    bf16*  qkv     = (bf16*)base;
    bf16*  vemb    = (bf16*)(base + 77070336);
    bf16*  attnout = (bf16*)(base + 77070336);
    bf16*  hbuf    = (bf16*)base;
    bf16*  wqkvb   = (bf16*)(base + 102760448);
    bf16*  wprojb  = wqkvb + 768 * 256;
    bf16*  fc1wb   = wprojb + 256 * 256;
    bf16*  fc2wb   = fc1wb + 1024 * 256;
    float* stats1  = (float*)(base + 104333312);
    float* stats2  = stats1 + 2 * M;

    cvt_w<<<192, 256, 0, stream>>>(wqkv, wqkvb, 768*256/4);
    cvt_w<<<64,  256, 0, stream>>>(wproj, wprojb, 256*256/4);
    cvt_w<<<256, 256, 0, stream>>>(fc1w, fc1wb, 1024*256/4);
    cvt_w<<<256, 256, 0, stream>>>(fc2w, fc2wb, 256*1024/4);

    stats_kernel<<<M / 4, 256, 0, stream>>>(x, stats1);
    vemb_kernel<<<M / 4, 256, 0, stream>>>(vote, vw1, vb1, vw2, vb2, vemb);

    dim3 gqkv(M / 128, 768 / 128);
    mfma_gemm<MODE_QKV><<<gqkv, 256, 0, stream>>>(x, wqkvb, bqkv, stats1, g1, be1, vemb, nullptr, qkv);

    attn_kernel<<<BT, 256, 0, stream>>>(qkv, polar, rw1, rb1, rw2, rb2, tau, mask, attnout);

    dim3 gproj(M / 128, 256 / 128);
    mfma_gemm<MODE_PROJ><<<gproj, 256, 0, stream>>>(attnout, wprojb, bproj, nullptr, nullptr, nullptr, nullptr, x, out);

    stats_kernel<<<M / 4, 256, 0, stream>>>(out, stats2);

    dim3 gfc1(M / 128, 1024 / 128);
    mfma_gemm<MODE_FC1><<<gfc1, 256, 0, stream>>>(out, fc1wb, fc1b, stats2, g2, be2, nullptr, nullptr, hbuf);

    dim3 gfc2(M / 128, 256 / 128);
    mfma_gemm<MODE_FC2><<<gfc2, 256, 0, stream>>>(hbuf, fc2wb, fc2b, nullptr, nullptr, nullptr, nullptr, out, out);
}